// Round 1
// baseline (210.541 us; speedup 1.0000x reference)
//
#include <hip/hip_runtime.h>
#include <math.h>

#define DMODEL 2048
#define NEXP   8
#define RANK   16
#define NPAIR  28   // unordered expert pairs C(8,2)

// ---------------- K1: router (logits -> top2 -> pair buckets) ----------------
__global__ __launch_bounds__(256, 2)
void router_kernel(const float* __restrict__ x,
                   const float* __restrict__ Wr,
                   const float* __restrict__ br,
                   float2* __restrict__ wparams,
                   int* __restrict__ cnt,
                   unsigned short* __restrict__ lists,
                   int nTok)
{
    __shared__ float wr_lds[DMODEL * NEXP];   // 64 KB
    const int tid = threadIdx.x;
    #pragma unroll
    for (int i = 0; i < 16; ++i) {
        const int f = (i*256 + tid)*4;
        *(float4*)&wr_lds[f] = *(const float4*)&Wr[f];
    }
    __syncthreads();

    const int s = tid >> 3;          // token slot 0..31
    const int j = tid & 7;           // d-lane 0..7
    const int tok = blockIdx.x*32 + s;
    const bool valid = tok < nTok;
    const float* xr = x + (size_t)(valid ? tok : 0) * DMODEL;

    float part[NEXP];
    #pragma unroll
    for (int e = 0; e < NEXP; ++e) part[e] = 0.f;

    for (int i = 0; i < 64; ++i) {
        const int d0 = (i*8 + j)*4;
        const float4 xv = *(const float4*)&xr[d0];
        #pragma unroll
        for (int q = 0; q < 4; ++q) {
            const float xq = (q==0)?xv.x:(q==1)?xv.y:(q==2)?xv.z:xv.w;
            const float4 w0 = *(const float4*)&wr_lds[(d0+q)*NEXP];
            const float4 w1 = *(const float4*)&wr_lds[(d0+q)*NEXP + 4];
            part[0] = fmaf(xq, w0.x, part[0]);
            part[1] = fmaf(xq, w0.y, part[1]);
            part[2] = fmaf(xq, w0.z, part[2]);
            part[3] = fmaf(xq, w0.w, part[3]);
            part[4] = fmaf(xq, w1.x, part[4]);
            part[5] = fmaf(xq, w1.y, part[5]);
            part[6] = fmaf(xq, w1.z, part[6]);
            part[7] = fmaf(xq, w1.w, part[7]);
        }
    }
    // reduce across the 8 j-lanes (consecutive lanes, xor butterfly)
    #pragma unroll
    for (int mres = 1; mres < 8; mres <<= 1) {
        #pragma unroll
        for (int e = 0; e < NEXP; ++e)
            part[e] += __shfl_xor(part[e], mres);
    }

    if (j == 0 && valid) {
        float lg[NEXP];
        #pragma unroll
        for (int e = 0; e < NEXP; ++e) lg[e] = part[e] + br[e];
        // top-1 (ties -> lowest index, matches lax.top_k)
        int b0 = 0; float v0 = lg[0];
        #pragma unroll
        for (int e = 1; e < NEXP; ++e) { if (lg[e] > v0) { v0 = lg[e]; b0 = e; } }
        // top-2
        int b1 = (b0 == 0) ? 1 : 0; float v1 = lg[b1];
        #pragma unroll
        for (int e = 0; e < NEXP; ++e) { if (e != b0 && lg[e] > v1) { v1 = lg[e]; b1 = e; } }
        // normalized top-2 gates: softmax denominators cancel exactly
        const float t = expf(v1 - v0);
        const float wtop = 1.f / (1.f + t);
        const float wsec = t / (1.f + t);
        const int lo = (b0 < b1) ? b0 : b1;
        const int hi = (b0 < b1) ? b1 : b0;
        const float wlo = (b0 < b1) ? wtop : wsec;
        const float whi = (b0 < b1) ? wsec : wtop;
        wparams[tok] = make_float2(wlo, whi);
        const int pidx = lo*(NEXP-1) - (lo*(lo-1))/2 + (hi - lo - 1);
        const int pos = atomicAdd(&cnt[pidx], 1);
        lists[(size_t)pidx*nTok + pos] = (unsigned short)tok;
    }
}

// ---------------- K2: fused down+up adapter per expert-pair bucket ----------------
__global__ __launch_bounds__(256, 2)
void moe_kernel(const float* __restrict__ x,
                const float* __restrict__ Wd,
                const float* __restrict__ bd,
                const float* __restrict__ Wu,
                const float* __restrict__ bu,
                const float2* __restrict__ wparams,
                const int* __restrict__ cnt,
                const unsigned short* __restrict__ lists,
                float* __restrict__ out,
                int nTok)
{
    const int p = blockIdx.x;      // pair bucket 0..27
    const int tile = blockIdx.y;
    const int n = cnt[p];
    if (tile*32 >= n) return;
    const int m = min(32, n - tile*32);

    // decode pair index -> (lo, hi)
    int lo = 0, rem = p;
    while (rem >= (NEXP-1-lo)) { rem -= (NEXP-1-lo); ++lo; }
    const int hi = lo + 1 + rem;

    __shared__ float x_lds[32][133];        // padded stride vs bank conflicts
    __shared__ float wd_lds[2][128][20];    // [k][d][r], stride 20 (aligned + bank-spread)
    __shared__ float wu_lds[2][16][128];    // [k][r][d]
    __shared__ float h_lds[2][16][32];      // [k][r][token]  (w folded in)
    __shared__ float bu_lds[2][128];
    __shared__ float w_lds[2][32];
    __shared__ int   tok_lds[32];

    const int tid = threadIdx.x;
    if (tid < 32) {
        const int idx = tile*32 + ((tid < m) ? tid : 0);   // clamp to a valid entry
        const int t = lists[(size_t)p*nTok + idx];
        tok_lds[tid] = t;
        const float2 w = wparams[t];
        w_lds[0][tid] = (tid < m) ? w.x : 0.f;
        w_lds[1][tid] = (tid < m) ? w.y : 0.f;
    }
    __syncthreads();

    // ---- Phase A: h[t][k][r] = relu(x . Wd[e_k] + bd) * w_k ----
    const int dg   = tid & 7;        // d-group (strided by 8 within chunk)
    const int unit = tid >> 3;       // (k, rh, tq)
    const int tq   = unit & 7;
    const int rh   = (unit >> 3) & 1;
    const int k    = unit >> 4;
    const int ek   = k ? hi : lo;
    const int rh8  = rh*8;

    float acc[4][8];
    #pragma unroll
    for (int i2 = 0; i2 < 4; ++i2)
        #pragma unroll
        for (int r2 = 0; r2 < 8; ++r2) acc[i2][r2] = 0.f;

    const int sA = tid >> 3;
    const int bA = tid & 7;

    for (int c = 0; c < 16; ++c) {
        { // stage x chunk [32 tokens][128 d]
            const float* xr = x + (size_t)tok_lds[sA]*DMODEL + c*128 + bA*16;
            const float4 v0 = *(const float4*)&xr[0];
            const float4 v1 = *(const float4*)&xr[4];
            const float4 v2 = *(const float4*)&xr[8];
            const float4 v3 = *(const float4*)&xr[12];
            float* dst = &x_lds[sA][bA*16];
            dst[0]=v0.x;  dst[1]=v0.y;  dst[2]=v0.z;  dst[3]=v0.w;
            dst[4]=v1.x;  dst[5]=v1.y;  dst[6]=v1.z;  dst[7]=v1.w;
            dst[8]=v2.x;  dst[9]=v2.y;  dst[10]=v2.z; dst[11]=v2.w;
            dst[12]=v3.x; dst[13]=v3.y; dst[14]=v3.z; dst[15]=v3.w;
        }
        // stage Wd chunk for both experts: contiguous 8KB per expert
        #pragma unroll
        for (int i2 = 0; i2 < 4; ++i2) {
            const int f   = (i2*256 + tid)*4;
            const int kk  = i2 >> 1;
            const int rr2 = f & 2047;
            const int dd  = rr2 >> 4;
            const int rr  = rr2 & 15;
            const int es  = kk ? hi : lo;
            const float4 v = *(const float4*)&Wd[(size_t)es*(DMODEL*RANK) + (size_t)c*(128*RANK) + rr2];
            *(float4*)&wd_lds[kk][dd][rr] = v;
        }
        __syncthreads();
        #pragma unroll
        for (int jj = 0; jj < 16; ++jj) {
            const int d = jj*8 + dg;
            const float4 wa = *(const float4*)&wd_lds[k][d][rh8];
            const float4 wb = *(const float4*)&wd_lds[k][d][rh8+4];
            #pragma unroll
            for (int i2 = 0; i2 < 4; ++i2) {
                const float xv = x_lds[tq*4 + i2][d];
                acc[i2][0] = fmaf(xv, wa.x, acc[i2][0]);
                acc[i2][1] = fmaf(xv, wa.y, acc[i2][1]);
                acc[i2][2] = fmaf(xv, wa.z, acc[i2][2]);
                acc[i2][3] = fmaf(xv, wa.w, acc[i2][3]);
                acc[i2][4] = fmaf(xv, wb.x, acc[i2][4]);
                acc[i2][5] = fmaf(xv, wb.y, acc[i2][5]);
                acc[i2][6] = fmaf(xv, wb.z, acc[i2][6]);
                acc[i2][7] = fmaf(xv, wb.w, acc[i2][7]);
            }
        }
        __syncthreads();
    }
    // reduce partials across the 8 dg lanes (consecutive)
    #pragma unroll
    for (int mm = 1; mm < 8; mm <<= 1) {
        #pragma unroll
        for (int i2 = 0; i2 < 4; ++i2)
            #pragma unroll
            for (int r2 = 0; r2 < 8; ++r2)
                acc[i2][r2] += __shfl_xor(acc[i2][r2], mm);
    }
    if (dg == 0) {
        #pragma unroll
        for (int r2 = 0; r2 < 8; ++r2) {
            const float bdv = bd[ek*RANK + rh8 + r2];
            float4 hv;
            hv.x = fmaxf(acc[0][r2] + bdv, 0.f) * w_lds[k][tq*4+0];
            hv.y = fmaxf(acc[1][r2] + bdv, 0.f) * w_lds[k][tq*4+1];
            hv.z = fmaxf(acc[2][r2] + bdv, 0.f) * w_lds[k][tq*4+2];
            hv.w = fmaxf(acc[3][r2] + bdv, 0.f) * w_lds[k][tq*4+3];
            *(float4*)&h_lds[k][rh8+r2][tq*4] = hv;
        }
    }
    __syncthreads();

    // ---- Phase B: out[t][d] = sum_k sum_r h'[k][r][t] * Wu[e_k][r][d] + sum_k w_k*bu[e_k][d] ----
    const int dgB = tid & 31;   // d-quad within chunk
    const int tqB = tid >> 5;   // token-quad

    for (int c = 0; c < 16; ++c) {
        #pragma unroll
        for (int i2 = 0; i2 < 4; ++i2) {
            const int f    = (i2*256 + tid)*4;
            const int kk   = i2 >> 1;
            const int rem2 = f & 2047;
            const int rr   = rem2 >> 7;
            const int dd   = rem2 & 127;
            const int es   = kk ? hi : lo;
            const float4 v = *(const float4*)&Wu[(size_t)es*(RANK*DMODEL) + (size_t)rr*DMODEL + c*128 + dd];
            *(float4*)&wu_lds[kk][rr][dd] = v;
        }
        if (tid < 64) {
            const int kk = tid >> 5;
            const int dd = (tid & 31)*4;
            const int es = kk ? hi : lo;
            *(float4*)&bu_lds[kk][dd] = *(const float4*)&bu[(size_t)es*DMODEL + c*128 + dd];
        }
        __syncthreads();

        float4 oa0 = {0,0,0,0}, oa1 = {0,0,0,0}, oa2 = {0,0,0,0}, oa3 = {0,0,0,0};
        #pragma unroll
        for (int k2 = 0; k2 < 2; ++k2) {
            #pragma unroll
            for (int r = 0; r < 16; ++r) {
                const float4 wu = *(const float4*)&wu_lds[k2][r][dgB*4];
                const float4 hv = *(const float4*)&h_lds[k2][r][tqB*4];
                oa0.x = fmaf(hv.x, wu.x, oa0.x); oa0.y = fmaf(hv.x, wu.y, oa0.y);
                oa0.z = fmaf(hv.x, wu.z, oa0.z); oa0.w = fmaf(hv.x, wu.w, oa0.w);
                oa1.x = fmaf(hv.y, wu.x, oa1.x); oa1.y = fmaf(hv.y, wu.y, oa1.y);
                oa1.z = fmaf(hv.y, wu.z, oa1.z); oa1.w = fmaf(hv.y, wu.w, oa1.w);
                oa2.x = fmaf(hv.z, wu.x, oa2.x); oa2.y = fmaf(hv.z, wu.y, oa2.y);
                oa2.z = fmaf(hv.z, wu.z, oa2.z); oa2.w = fmaf(hv.z, wu.w, oa2.w);
                oa3.x = fmaf(hv.w, wu.x, oa3.x); oa3.y = fmaf(hv.w, wu.y, oa3.y);
                oa3.z = fmaf(hv.w, wu.z, oa3.z); oa3.w = fmaf(hv.w, wu.w, oa3.w);
            }
        }
        const float4 blo = *(const float4*)&bu_lds[0][dgB*4];
        const float4 bhi = *(const float4*)&bu_lds[1][dgB*4];
        float4 oas[4] = {oa0, oa1, oa2, oa3};
        #pragma unroll
        for (int i2 = 0; i2 < 4; ++i2) {
            const float wl = w_lds[0][tqB*4+i2];
            const float wh = w_lds[1][tqB*4+i2];
            float4 o = oas[i2];
            o.x += wl*blo.x + wh*bhi.x;
            o.y += wl*blo.y + wh*bhi.y;
            o.z += wl*blo.z + wh*bhi.z;
            o.w += wl*blo.w + wh*bhi.w;
            const int slot = tqB*4 + i2;
            if (slot < m) {
                *(float4*)&out[(size_t)tok_lds[slot]*DMODEL + (size_t)c*128 + dgB*4] = o;
            }
        }
        __syncthreads();
    }
}

extern "C" void kernel_launch(void* const* d_in, const int* in_sizes, int n_in,
                              void* d_out, int out_size, void* d_ws, size_t ws_size,
                              hipStream_t stream)
{
    (void)n_in; (void)out_size; (void)ws_size;
    const float* x  = (const float*)d_in[0];
    const float* Wr = (const float*)d_in[1];
    const float* br = (const float*)d_in[2];
    const float* Wd = (const float*)d_in[3];
    const float* bd = (const float*)d_in[4];
    const float* Wu = (const float*)d_in[5];
    const float* bu = (const float*)d_in[6];
    float* out = (float*)d_out;
    const int nTok = in_sizes[0] / DMODEL;   // 8192

    // workspace layout: [cnt: 28 ints, padded to 256B][wparams: nTok float2][lists: 28*nTok u16]
    int* cnt = (int*)d_ws;
    float2* wparams = (float2*)((char*)d_ws + 256);
    unsigned short* lists = (unsigned short*)((char*)d_ws + 256 + (size_t)nTok*sizeof(float2));

    hipMemsetAsync(d_ws, 0, 256, stream);
    const int ntiles = (nTok + 31)/32;
    router_kernel<<<ntiles, 256, 0, stream>>>(x, Wr, br, wparams, cnt, lists, nTok);
    dim3 g2(NPAIR, ntiles);
    moe_kernel<<<g2, 256, 0, stream>>>(x, Wd, bd, Wu, bu, wparams, cnt, lists, out, nTok);
}